// Round 3
// baseline (256.190 us; speedup 1.0000x reference)
//
#include <hip/hip_runtime.h>
#include <hip/hip_fp16.h>

#define NN 8192
#define INF 256
#define OUTF 128
#define LOG2E 1.44269504088896340736f

typedef float f32x4 __attribute__((ext_vector_type(4)));
typedef float f32x16 __attribute__((ext_vector_type(16)));
typedef __fp16 h16x8 __attribute__((ext_vector_type(8)));
typedef __fp16 h16x4 __attribute__((ext_vector_type(4)));
typedef __fp16 h16x2 __attribute__((ext_vector_type(2)));
typedef int i32x4 __attribute__((ext_vector_type(4)));

// ---------------- KB: adj int32 -> bitmask uint64[8192][128] (8 MB) via ballot
__global__ __launch_bounds__(256) void kb_mask(const int* __restrict__ adj,
                                               unsigned long long* __restrict__ adjb) {
  size_t gid = (size_t)blockIdx.x * 256 + threadIdx.x;
#pragma unroll 8
  for (int it = 0; it < 128; ++it) {
    size_t idx = (size_t)it * 524288 + gid;
    int v = adj[idx];
    unsigned long long m = __ballot(v != 0);
    if ((threadIdx.x & 63) == 0) adjb[idx >> 6] = m;
  }
}

// ---------------- K0: W (256x128 f32) -> WT_perm f16 (for K1's 32x32x16 MFMA)
__global__ __launch_bounds__(256) void k0_wt(const float* __restrict__ W1,
                                             const float* __restrict__ W2,
                                             __fp16* __restrict__ WT) {
  int m = blockIdx.x * 256 + threadIdx.x;  // 8192 chunks of 16B
  int h = m >> 12;
  int r = m & 4095;
  int c = r >> 5;
  int kb = (r >> 1) & 15;
  int hh = r & 1;
  const float* W = h ? W2 : W1;
  float v[8];
#pragma unroll
  for (int s = 0; s < 8; ++s) {
    int koff = 4 * hh + (s & 3) + 8 * (s >> 2);
    v[s] = W[(kb * 16 + koff) * OUTF + c];
  }
  union { h16x2 h2[4]; i32x4 q; } u;
  u.h2[0] = __builtin_amdgcn_cvt_pkrtz(v[0], v[1]);
  u.h2[1] = __builtin_amdgcn_cvt_pkrtz(v[2], v[3]);
  u.h2[2] = __builtin_amdgcn_cvt_pkrtz(v[4], v[5]);
  u.h2[3] = __builtin_amdgcn_cvt_pkrtz(v[6], v[7]);
  *(i32x4*)(WT + (size_t)h * 32768 + c * 256 + kb * 16 + hh * 8) = u.q;
}

// ---------------- K1: h = inp@W via MFMA; emits hT_perm16 (16x16x32 B-frag layout),
// src' and dst' scaled by log2e
__global__ __launch_bounds__(128) void k1_h(
    const float* __restrict__ inp, const __fp16* __restrict__ WT,
    const float* __restrict__ a1, const float* __restrict__ a2,
    __fp16* __restrict__ hT, float* __restrict__ S, float* __restrict__ D) {
  __shared__ __align__(16) float hl[2][32][136];
  int tid = threadIdx.x;
  int w = tid >> 6;           // wave = head
  int l = tid & 63;
  int lr = l & 31, g = l >> 5;
  int i0 = blockIdx.x * 32;
  const __fp16* WTh = WT + (size_t)w * 32768;
  f32x16 acc[4];
#pragma unroll
  for (int nf = 0; nf < 4; ++nf)
#pragma unroll
    for (int e = 0; e < 16; ++e) acc[nf][e] = 0.0f;
  const float* ip = inp + (size_t)(i0 + lr) * INF;
#pragma unroll
  for (int kb = 0; kb < 16; ++kb) {
    f32x4 q0 = *(const f32x4*)(ip + kb * 16 + 4 * g);
    f32x4 q1 = *(const f32x4*)(ip + kb * 16 + 8 + 4 * g);
    union { h16x2 h2[4]; h16x8 h8; } ua;
    ua.h2[0] = __builtin_amdgcn_cvt_pkrtz(q0[0], q0[1]);
    ua.h2[1] = __builtin_amdgcn_cvt_pkrtz(q0[2], q0[3]);
    ua.h2[2] = __builtin_amdgcn_cvt_pkrtz(q1[0], q1[1]);
    ua.h2[3] = __builtin_amdgcn_cvt_pkrtz(q1[2], q1[3]);
#pragma unroll
    for (int nf = 0; nf < 4; ++nf) {
      h16x8 b = *(const h16x8*)(WTh + (nf * 32 + lr) * 256 + kb * 16 + g * 8);
      acc[nf] = __builtin_amdgcn_mfma_f32_32x32x16_f16(ua.h8, b, acc[nf], 0, 0, 0);
    }
  }
#pragma unroll
  for (int nf = 0; nf < 4; ++nf)
#pragma unroll
    for (int r = 0; r < 16; ++r) {
      int row = (r & 3) + 8 * (r >> 2) + 4 * g;
      hl[w][row][nf * 32 + lr] = acc[nf][r];
    }
  __syncthreads();
  const float* av = w ? a2 : a1;
  float s = 0.f, d = 0.f;
#pragma unroll
  for (int cc = 0; cc < 64; cc += 4) {
    int c = g * 64 + cc;
    f32x4 hv = *(const f32x4*)&hl[w][lr][c];
    f32x4 as = *(const f32x4*)(av + c);
    f32x4 ad = *(const f32x4*)(av + 128 + c);
    s += hv[0] * as[0] + hv[1] * as[1] + hv[2] * as[2] + hv[3] * as[3];
    d += hv[0] * ad[0] + hv[1] * ad[1] + hv[2] * ad[2] + hv[3] * ad[3];
  }
  s += __shfl_xor(s, 32);
  d += __shfl_xor(d, 32);
  if (g == 0) {
    S[(size_t)w * NN + i0 + lr] = s * LOG2E;
    D[(size_t)w * NN + i0 + lr] = d * LOG2E;
  }
  // hT_perm16: [head][jb32][col128][g4][8slots] f16; jb32 = blockIdx.x (rows i0..i0+31)
  __fp16* hTh = hT + (size_t)w * (NN * OUTF) + (size_t)blockIdx.x * 4096;
#pragma unroll
  for (int it = 0; it < 8; ++it) {
    int m = it * 64 + l;            // 512 16B-chunks
    int col = m & 127, gw = m >> 7; // gw = k-group 0..3
    float v[8];
#pragma unroll
    for (int s2 = 0; s2 < 8; ++s2) v[s2] = hl[w][gw * 8 + s2][col];
    union { h16x2 h2[4]; i32x4 q; } u2;
    u2.h2[0] = __builtin_amdgcn_cvt_pkrtz(v[0], v[1]);
    u2.h2[1] = __builtin_amdgcn_cvt_pkrtz(v[2], v[3]);
    u2.h2[2] = __builtin_amdgcn_cvt_pkrtz(v[4], v[5]);
    u2.h2[3] = __builtin_amdgcn_cvt_pkrtz(v[6], v[7]);
    *(i32x4*)(hTh + col * 32 + gw * 8) = u2.q;
  }
}

// ---------------- K1c: gmax' per head
__global__ __launch_bounds__(256) void k1c_gmax(const float* __restrict__ D,
                                                float* __restrict__ GM) {
  __shared__ float r1[256], r2[256];
  int t = threadIdx.x;
  float m1 = -1e30f, m2 = -1e30f;
  for (int i = t; i < NN; i += 256) {
    m1 = fmaxf(m1, D[i]);
    m2 = fmaxf(m2, D[NN + i]);
  }
  r1[t] = m1; r2[t] = m2;
  __syncthreads();
  for (int s = 128; s > 0; s >>= 1) {
    if (t < s) { r1[t] = fmaxf(r1[t], r1[t + s]); r2[t] = fmaxf(r2[t], r2[t + s]); }
    __syncthreads();
  }
  if (t == 0) { GM[0] = r1[0]; GM[1] = r2[0]; }
}

// ---------------- K2: fused mask+softmax+PV. No LDS; 4 waves = 2 heads x 2 rowgroups
// of 16 rows; grid = 256 rowblocks(BM=32) x 4 js; js == XCD&3 for L2 locality.
__global__ __launch_bounds__(256, 4) void k2_attn(
    const unsigned long long* __restrict__ adjb, const __fp16* __restrict__ hT,
    const float* __restrict__ S, const float* __restrict__ D,
    const float* __restrict__ GM, __fp16* __restrict__ NUM, float* __restrict__ DEN) {
  int tid = threadIdx.x;
  int w = tid >> 6;
  int l = tid & 63;
  int c16 = l & 15, g4 = l >> 4;
  int h = w >> 1, rg = w & 1;
  int rb = blockIdx.x >> 2, js = blockIdx.x & 3;
  int i0 = rb * 32;
  int row = i0 + rg * 16 + c16;
  float sf = S[(size_t)h * NN + row];
  float gm = GM[h];
  float v0 = sf + gm;
  float cneg = -fmaxf(v0, 0.2f * v0) - 1000.0f;  // arg = LRelu' + cneg + bit*1000
  const __fp16* hTh = hT + (size_t)h * (NN * OUTF) + (size_t)js * 64 * 4096 +
                      c16 * 32 + g4 * 8;
  const float* Dh = D + (size_t)h * NN + js * 2048 + g4 * 8;
  const unsigned long long* mrow = adjb + (size_t)row * 128 + js * 32;

  f32x4 acc[8];
#pragma unroll
  for (int nf = 0; nf < 8; ++nf) acc[nf] = {0.f, 0.f, 0.f, 0.f};
  float dsum = 0.f;

  for (int kq = 0; kq < 16; ++kq) {
    i32x4 mw = *(const i32x4*)(mrow + kq * 2);  // 2 u64 = bits for 128 j
#pragma unroll
    for (int k2 = 0; k2 < 4; ++k2) {
      int ks = kq * 4 + k2;
      unsigned int bits = ((unsigned int)mw[k2]) >> (g4 * 8);  // s-bits in low byte
      f32x4 d0 = *(const f32x4*)(Dh + ks * 32);
      f32x4 d1 = *(const f32x4*)(Dh + ks * 32 + 4);
      float pv[8];
#pragma unroll
      for (int s = 0; s < 8; ++s) {
        float dd = (s < 4) ? d0[s] : d1[s - 4];
        float tt = sf + dd;
        float u = fmaxf(tt, 0.2f * tt) + cneg;       // LeakyReLU (log2-scaled) - m' - 1000
        float bf = (float)((bits >> s) & 1u);
        pv[s] = exp2f(fmaf(bf, 1000.0f, u));         // masked -> exact 0
      }
      dsum += ((pv[0] + pv[1]) + (pv[2] + pv[3])) + ((pv[4] + pv[5]) + (pv[6] + pv[7]));
      union { h16x2 h2[4]; h16x8 h8; } up;
      up.h2[0] = __builtin_amdgcn_cvt_pkrtz(pv[0], pv[1]);
      up.h2[1] = __builtin_amdgcn_cvt_pkrtz(pv[2], pv[3]);
      up.h2[2] = __builtin_amdgcn_cvt_pkrtz(pv[4], pv[5]);
      up.h2[3] = __builtin_amdgcn_cvt_pkrtz(pv[6], pv[7]);
      const __fp16* hb = hTh + (size_t)ks * 4096;
#pragma unroll
      for (int nf = 0; nf < 8; ++nf) {
        h16x8 Bf = *(const h16x8*)(hb + nf * 512);   // col = nf*16 + c16
        acc[nf] = __builtin_amdgcn_mfma_f32_16x16x32_f16(up.h8, Bf, acc[nf], 0, 0, 0);
      }
    }
  }
  // denom: reduce the 4 k-groups (lanes sharing c16)
  dsum += __shfl_xor(dsum, 16);
  dsum += __shfl_xor(dsum, 32);
  if (g4 == 0) DEN[(size_t)(js * 2 + h) * NN + row] = dsum;
  // C layout (16x16): col = c16, crow = g4*4 + r
  __fp16* nb = NUM + ((size_t)(js * 2 + h) * NN + i0 + rg * 16 + g4 * 4) * 128 + c16;
#pragma unroll
  for (int nf = 0; nf < 8; ++nf)
#pragma unroll
    for (int r = 0; r < 4; ++r)
      nb[(size_t)r * 128 + nf * 16] = (__fp16)acc[nf][r];
}

// ---------------- K3: merge js partials, combine heads, ELU
__global__ __launch_bounds__(256) void k3_out(const __fp16* __restrict__ NUM,
                                              const float* __restrict__ DEN,
                                              float* __restrict__ out) {
  int gid = blockIdx.x * 256 + threadIdx.x;  // 262144
  int i = gid >> 5;
  int c4 = (gid & 31) * 4;
  f32x4 n1 = {0.f, 0.f, 0.f, 0.f}, n2 = {0.f, 0.f, 0.f, 0.f};
  float d1 = 0.f, d2 = 0.f;
#pragma unroll
  for (int js = 0; js < 4; ++js) {
    h16x4 a1v = *(const h16x4*)(NUM + ((size_t)(js * 2 + 0) * NN + i) * 128 + c4);
    h16x4 a2v = *(const h16x4*)(NUM + ((size_t)(js * 2 + 1) * NN + i) * 128 + c4);
#pragma unroll
    for (int e = 0; e < 4; ++e) { n1[e] += (float)a1v[e]; n2[e] += (float)a2v[e]; }
    d1 += DEN[(size_t)(js * 2 + 0) * NN + i];
    d2 += DEN[(size_t)(js * 2 + 1) * NN + i];
  }
  float r1 = 1.0f / d1, r2 = 0.5f / d2;
  f32x4 o;
#pragma unroll
  for (int e = 0; e < 4; ++e) {
    float x = n1[e] * r1 + n2[e] * r2;
    o[e] = x > 0.f ? x : (exp2f(x * LOG2E) - 1.0f);
  }
  *(f32x4*)(out + (size_t)i * 128 + c4) = o;
}

extern "C" void kernel_launch(void* const* d_in, const int* in_sizes, int n_in,
                              void* d_out, int out_size, void* d_ws, size_t ws_size,
                              hipStream_t stream) {
  const float* inp = (const float*)d_in[0];
  const int* adj = (const int*)d_in[1];
  const float* W1 = (const float*)d_in[2];
  const float* a1 = (const float*)d_in[3];
  const float* W2 = (const float*)d_in[4];
  const float* a2 = (const float*)d_in[5];
  float* out = (float*)d_out;
  char* ws = (char*)d_ws;
  // ws layout (~28.5 MB):
  __fp16* WT = (__fp16*)(ws);                              // 131072 B
  __fp16* hT = (__fp16*)(ws + 131072);                     // 4 MB
  float* S = (float*)(ws + 4325376);                       // 64 KB
  float* D = (float*)(ws + 4390912);                       // 64 KB
  float* GM = (float*)(ws + 4456448);                      // 256 B
  unsigned long long* adjb = (unsigned long long*)(ws + 4456704);  // 8 MB
  __fp16* NUM = (__fp16*)(ws + 12845312);                  // 16 MB (f16 partials)
  float* DEN = (float*)(ws + 29622528);                    // 256 KB

  kb_mask<<<dim3(2048), dim3(256), 0, stream>>>(adj, adjb);
  k0_wt<<<dim3(32), dim3(256), 0, stream>>>(W1, W2, WT);
  k1_h<<<dim3(256), dim3(128), 0, stream>>>(inp, WT, a1, a2, hT, S, D);
  k1c_gmax<<<dim3(1), dim3(256), 0, stream>>>(D, GM);
  k2_attn<<<dim3(1024), dim3(256), 0, stream>>>(adjb, hT, S, D, GM, NUM, DEN);
  k3_out<<<dim3(1024), dim3(256), 0, stream>>>(NUM, DEN, out);
}